// Round 12
// baseline (20.177 us; speedup 1.0000x reference)
//
#include <hip/hip_runtime.h>
#include <cfloat>

#define BB   1024
#define PP   32
#define NNEG 64
#define DD   64
#define BSTR 72   // bf16 LDS row stride (144 B, 16B-aligned)
#define SSTR 68   // s_lds row stride in floats (272 B, 16B-aligned rows)

static constexpr float W2c = 0.1f;

typedef __attribute__((ext_vector_type(8)))  short bf16x8;
typedef __attribute__((ext_vector_type(16))) float f32x16;

// Pack float4 -> 4 bf16 via v_cvt_pk_bf16_f32. Pair order within each word is
// a shared k-permutation on both MFMA operands -> Gram dot invariant.
__device__ __forceinline__ uint2 pk_bf16x4(float4 v) {
    unsigned a, b;
    asm("v_cvt_pk_bf16_f32 %0, %1, %2" : "=v"(a) : "v"(v.x), "v"(v.y));
    asm("v_cvt_pk_bf16_f32 %0, %1, %2" : "=v"(b) : "v"(v.z), "v"(v.w));
    return make_uint2(a, b);
}

__device__ __forceinline__ float parse_mask(const void* p, int flag, int j) {
    if (flag == 1) return ((const unsigned char*)p)[j] ? 1.0f : 0.0f;
    if (flag == 2) return (((const float*)p)[j] != 0.0f) ? 1.0f : 0.0f;
    return ((const int*)p)[j] ? 1.0f : 0.0f;
}

// ---------------------------------------------------------------------------
// TWO batch elements per block (512 blocks x 512 threads): all gathers for
// both elements issue back-to-back in phase A (2x MLP, b1 latency hidden
// under b0's), one barrier set shared, phase-B work spread over all 8 waves
// (w0-3 MFMA, w4-5 sort/scan/a2a3, w6-7 uu). No cross-block coherence.
// ---------------------------------------------------------------------------
__global__ __launch_bounds__(512, 4) void loss_kernel(
    const float* __restrict__ u2e, const float* __restrict__ v2e,
    const float* __restrict__ margin_uv, const float* __restrict__ margin_vv,
    const float* __restrict__ margin_uu,
    const int* __restrict__ train_u, const int* __restrict__ pos_idx,
    const int* __restrict__ neg_idx, const int* __restrict__ nb_idx,
    const int* __restrict__ nn_idx,
    const void* __restrict__ pos_mask, const void* __restrict__ neg_mask,
    const void* __restrict__ nb_mask, const void* __restrict__ nn_mask,
    float* __restrict__ ws) {

    const int t = threadIdx.x;
    const int lane = t & 63;
    const int w = t >> 6;
    const int bb0 = blockIdx.x * 2;

    __shared__ __align__(16) short pn_bf[2][96 * BSTR];
    __shared__ __align__(16) float s_lds[2][PP * SSTR];
    __shared__ __align__(16) float d2_[2][NNEG], n2_[2][NNEG], nmf_[2][NNEG];
    __shared__ float d1_[2][PP], p2_[2][PP], d1s_[2][PP], d2s_[2][PP];
    __shared__ float pmf_[2][PP], nbmf_[2][PP], nnmf_[2][PP];
    __shared__ float mvp_[2][PP], mva_[2][PP], srt_[2][PP], suf_[2][PP + 1];
    __shared__ float sc_[2][2];
    __shared__ float red[8][2];
    __shared__ float uu_red[2];
    __shared__ float a23[2][2];

    // ---- Phase A (no barriers) -------------------------------------------
    // Mask-layout sniff, 1KB window, all waves (waves 0-2 and 4-6 consume).
    int flag;
    {
        unsigned f32h = 0, byth = 0;
        #pragma unroll
        for (int i2 = 0; i2 < 4; ++i2) {
            unsigned mw = ((const unsigned int*)pos_mask)[lane + 64 * i2];
            f32h |= (mw == 0x3f800000u) ? 1u : 0u;
            byth |= ((mw != 0x3f800000u) && (mw & 0xFFFFFF00u)) ? 1u : 0u;
        }
        flag = __any(f32h) ? 2 : (__any(byth) ? 1 : 0);
    }

    const int q   = t & 15;          // column chunk
    const int R0  = t >> 4;          // 0..31
    const int row = t >> 3, sub = t & 7;

    // Index loads for BOTH elements back-to-back
    int tu[2], gi0[2], gi1[2], gi2[2], sidx[2];
    #pragma unroll
    for (int j = 0; j < 2; ++j) {
        const int b = bb0 + j;
        tu[j]   = train_u[b];
        gi0[j]  = pos_idx[b * PP + R0];
        gi1[j]  = neg_idx[b * NNEG + R0];
        gi2[j]  = neg_idx[b * NNEG + R0 + 32];
        sidx[j] = (row < PP) ? nb_idx[b * PP + row] : nn_idx[b * PP + row - PP];
    }

    // Row loads for BOTH elements back-to-back (max MLP: ~16 in flight)
    float4 u4[2], ch0[2], ch1[2], ch2[2], e0[2], e1[2], v0[2], v1[2];
    #pragma unroll
    for (int j = 0; j < 2; ++j) {
        const float* uR = u2e + (size_t)tu[j] * DD;
        u4[j]  = *(const float4*)(uR + 4 * q);
        ch0[j] = *(const float4*)(v2e + (size_t)gi0[j] * DD + 4 * q);
        ch1[j] = *(const float4*)(v2e + (size_t)gi1[j] * DD + 4 * q);
        ch2[j] = *(const float4*)(v2e + (size_t)gi2[j] * DD + 4 * q);
        const float* rp = u2e + (size_t)sidx[j] * DD + 8 * sub;
        e0[j] = *(const float4*)(rp);
        e1[j] = *(const float4*)(rp + 4);
        v0[j] = *(const float4*)(uR + 8 * sub);
        v1[j] = *(const float4*)(uR + 8 * sub + 4);
    }

    // p/n row stats + nb/nn stats + staging, per element
    #pragma unroll
    for (int j = 0; j < 2; ++j) {
        float sdp[3], sqp[3];
        float dx, dy, dz, dw;
        dx = ch0[j].x-u4[j].x; dy = ch0[j].y-u4[j].y; dz = ch0[j].z-u4[j].z; dw = ch0[j].w-u4[j].w;
        sdp[0] = dx*dx+dy*dy+dz*dz+dw*dw;
        sqp[0] = ch0[j].x*ch0[j].x+ch0[j].y*ch0[j].y+ch0[j].z*ch0[j].z+ch0[j].w*ch0[j].w;
        dx = ch1[j].x-u4[j].x; dy = ch1[j].y-u4[j].y; dz = ch1[j].z-u4[j].z; dw = ch1[j].w-u4[j].w;
        sdp[1] = dx*dx+dy*dy+dz*dz+dw*dw;
        sqp[1] = ch1[j].x*ch1[j].x+ch1[j].y*ch1[j].y+ch1[j].z*ch1[j].z+ch1[j].w*ch1[j].w;
        dx = ch2[j].x-u4[j].x; dy = ch2[j].y-u4[j].y; dz = ch2[j].z-u4[j].z; dw = ch2[j].w-u4[j].w;
        sdp[2] = dx*dx+dy*dy+dz*dz+dw*dw;
        sqp[2] = ch2[j].x*ch2[j].x+ch2[j].y*ch2[j].y+ch2[j].z*ch2[j].z+ch2[j].w*ch2[j].w;
        #pragma unroll
        for (int m = 1; m < 16; m <<= 1) {
            #pragma unroll
            for (int r = 0; r < 3; ++r) {
                sdp[r] += __shfl_xor(sdp[r], m);
                sqp[r] += __shfl_xor(sqp[r], m);
            }
        }
        if (q == 0) {
            d1_[j][R0]      = sdp[0]; p2_[j][R0]      = sqp[0];
            d2_[j][R0]      = sdp[1]; n2_[j][R0]      = sqp[1];
            d2_[j][R0 + 32] = sdp[2]; n2_[j][R0 + 32] = sqp[2];
        }
        float ex = e0[j].x-v0[j].x, ey = e0[j].y-v0[j].y, ez = e0[j].z-v0[j].z, ew = e0[j].w-v0[j].w;
        float s = ex*ex+ey*ey+ez*ez+ew*ew;
        ex = e1[j].x-v1[j].x; ey = e1[j].y-v1[j].y; ez = e1[j].z-v1[j].z; ew = e1[j].w-v1[j].w;
        s += ex*ex+ey*ey+ez*ez+ew*ew;
        s += __shfl_xor(s, 1);
        s += __shfl_xor(s, 2);
        s += __shfl_xor(s, 4);
        if (sub == 0) { if (row < PP) d1s_[j][row] = s; else d2s_[j][row - PP] = s; }
        // bf16 staging
        *(uint2*)(pn_bf[j] + R0 * BSTR + 4 * q)        = pk_bf16x4(ch0[j]);
        *(uint2*)(pn_bf[j] + (R0 + 32) * BSTR + 4 * q) = pk_bf16x4(ch1[j]);
        *(uint2*)(pn_bf[j] + (R0 + 64) * BSTR + 4 * q) = pk_bf16x4(ch2[j]);
    }

    // masks + margins: threads [0,160) -> element 0, [256,416) -> element 1
    {
        const int j  = (t >= 256) ? 1 : 0;
        const int tt = t - 256 * j;
        const int b  = bb0 + j;
        if (tt < PP) {
            float pm = parse_mask(pos_mask, flag, b * PP + tt);
            float mv = margin_vv[pos_idx[b * PP + tt]];
            pmf_[j][tt] = pm; mva_[j][tt] = mv;
            mvp_[j][tt] = (pm != 0.0f) ? mv : -FLT_MAX;
        } else if (tt < 96) {
            nmf_[j][tt - PP] = parse_mask(neg_mask, flag, b * NNEG + (tt - PP));
        } else if (tt < 128) {
            nbmf_[j][tt - 96] = parse_mask(nb_mask, flag, b * PP + (tt - 96));
        } else if (tt < 160) {
            nnmf_[j][tt - 128] = parse_mask(nn_mask, flag, b * PP + (tt - 128));
        }
        if (tt == 0) { sc_[j][0] = margin_uv[tu[j]]; sc_[j][1] = margin_uu[tu[j]]; }
    }
    __syncthreads();   // barrier 1

    // ---- Phase B: all 8 waves busy ---------------------------------------
    if (w < 4) {
        // MFMA Gram: waves 0-1 -> element 0, waves 2-3 -> element 1
        const int j    = w >> 1;
        const int half = w & 1;
        f32x16 acc;
        #pragma unroll
        for (int i = 0; i < 16; ++i) acc[i] = 0.0f;
        const int lr = lane & 31;
        const int hi = lane >> 5;
        const short* ap = pn_bf[j] + lr * BSTR;
        const short* bp = pn_bf[j] + (PP + 32 * half + lr) * BSTR;
        #pragma unroll
        for (int c = 0; c < 4; ++c) {
            const int d0 = 16 * c + 8 * hi;
            bf16x8 a   = *(const bf16x8*)(ap + d0);
            bf16x8 bfr = *(const bf16x8*)(bp + d0);
            acc = __builtin_amdgcn_mfma_f32_32x32x16_bf16(a, bfr, acc, 0, 0, 0);
        }
        #pragma unroll
        for (int r = 0; r < 16; ++r) {
            const int m = (r & 3) + 8 * (r >> 2) + 4 * hi;      // verified C/D mapping
            s_lds[j][m * SSTR + 32 * half + lr] = acc[r];
        }
    } else if (w < 6) {
        // sort + suffix scan + a2/a3 for element j = w-4
        const int j = w - 4;
        if (lane < PP) {
            float vj = mvp_[j][lane];
            int r = 0;
            #pragma unroll
            for (int j2 = 0; j2 < PP; ++j2) {
                float o = mvp_[j][j2];
                r += (o < vj || (o == vj && j2 < lane)) ? 1 : 0;
            }
            srt_[j][r] = vj;
        }
        __threadfence_block();
        if (lane < PP) {
            float y = srt_[j][lane];
            #pragma unroll
            for (int d = 1; d < PP; d <<= 1) {
                float z = __shfl_down(y, d);
                if (lane + d < PP) y += z;
            }
            suf_[j][lane] = y;
            if (lane == 0) suf_[j][PP] = 0.0f;
        }
        float a2 = (lane < PP) ? mva_[j][lane] * pmf_[j][lane] : 0.0f;
        float a3 = (lane < PP) ? pmf_[j][lane] : 0.0f;
        #pragma unroll
        for (int m = 1; m < 64; m <<= 1) {
            a2 += __shfl_xor(a2, m);
            a3 += __shfl_xor(a3, m);
        }
        if (lane == 0) { a23[j][0] = a2; a23[j][1] = a3; }
    } else {
        // uu loss for element j = w-6: 1024 pairs, 16 per lane
        const int j = w - 6;
        const float m_s = sc_[j][1];
        float uul = 0.0f;
        #pragma unroll
        for (int r = 0; r < 16; ++r) {
            const int pid = lane + 64 * r;
            const int ii = pid >> 5, k = pid & 31;
            uul += nbmf_[j][ii] * nnmf_[j][k] * fmaxf(m_s + d1s_[j][ii] - d2s_[j][k], 0.0f);
        }
        #pragma unroll
        for (int m = 1; m < 64; m <<= 1) uul += __shfl_xor(uul, m);
        if (lane == 0) uu_red[j] = uul;
    }
    __syncthreads();   // barrier 2

    // ---- Phase C: vv + uv epilogue for both elements ----------------------
    const int kb2 = t & 15;
    const int i   = R0;
    float loss[2];
    #pragma unroll
    for (int j = 0; j < 2; ++j) {
        const float m_u = sc_[j][0];
        const float s31 = srt_[j][PP - 1];
        const float d1i = d1_[j][i], p2i = p2_[j][i], pmi = pmf_[j][i];
        const float4 Sv  = *(const float4*)(s_lds[j] + i * SSTR + 4 * kb2);
        const float4 d2v = *(const float4*)(d2_[j] + 4 * kb2);
        const float4 n2v = *(const float4*)(n2_[j] + 4 * kb2);
        const float4 nmv = *(const float4*)(nmf_[j] + 4 * kb2);
        const float Sa[4]  = {Sv.x, Sv.y, Sv.z, Sv.w};
        const float d2a[4] = {d2v.x, d2v.y, d2v.z, d2v.w};
        const float n2a[4] = {n2v.x, n2v.y, n2v.z, n2v.w};
        const float nma[4] = {nmv.x, nmv.y, nmv.z, nmv.w};
        float L = 0.0f;
        #pragma unroll
        for (int c = 0; c < 4; ++c) {
            const float cc = d1i - (p2i + n2a[c] - 2.0f * Sa[c]);
            const float v = -cc;
            int t0 = 0;
            #pragma unroll
            for (int st = 16; st > 0; st >>= 1)
                t0 += (srt_[j][t0 + st - 1] <= v) ? st : 0;
            t0 += (s31 <= v) ? 1 : 0;
            const float inner = suf_[j][t0] + (float)(PP - t0) * cc;
            const float uvh = fmaxf(m_u + d1i - d2a[c], 0.0f);
            L += pmi * nma[c] * (inner + uvh);
        }
        loss[j] = L;
    }
    #pragma unroll
    for (int m = 1; m < 64; m <<= 1) {
        loss[0] += __shfl_xor(loss[0], m);
        loss[1] += __shfl_xor(loss[1], m);
    }
    if (lane == 0) { red[w][0] = loss[0]; red[w][1] = loss[1]; }
    __syncthreads();   // barrier 3

    if (t == 0) {
        #pragma unroll
        for (int j = 0; j < 2; ++j) {
            float S0 = uu_red[j];
            #pragma unroll
            for (int i2 = 0; i2 < 8; ++i2) S0 += red[i2][j];
            const int b = bb0 + j;
            ws[0 * BB + b] = S0;
            ws[1 * BB + b] = sc_[j][0];
            ws[2 * BB + b] = a23[j][0];
            ws[3 * BB + b] = a23[j][1];
            ws[4 * BB + b] = sc_[j][1];
        }
    }
}

// ---------------------------------------------------------------------------
// Finalize: single wave, fully-coalesced float4 loads (20 KB total).
// ---------------------------------------------------------------------------
__global__ __launch_bounds__(64) void finalize_kernel(const float* __restrict__ ws,
                                                      float* __restrict__ out) {
    const int lane = threadIdx.x;
    float s[5];
    #pragma unroll
    for (int a = 0; a < 5; ++a) {
        const float4* w4 = (const float4*)(ws + a * BB);
        float acc = 0.0f;
        #pragma unroll
        for (int j = 0; j < 4; ++j) {
            float4 v = w4[lane + 64 * j];
            acc += v.x + v.y + v.z + v.w;
        }
        s[a] = acc;
    }
    #pragma unroll
    for (int m = 1; m < 64; m <<= 1)
        #pragma unroll
        for (int a = 0; a < 5; ++a) s[a] += __shfl_xor(s[a], m);
    if (lane == 0) {
        float loss_am = s[1] / (float)BB + s[2] / s[3] + s[4] / (float)BB;
        out[0] = s[0] + W2c * loss_am;
    }
}

extern "C" void kernel_launch(void* const* d_in, const int* in_sizes, int n_in,
                              void* d_out, int out_size, void* d_ws, size_t ws_size,
                              hipStream_t stream) {
    const float* u2e       = (const float*)d_in[0];
    const float* v2e       = (const float*)d_in[1];
    const float* margin_uv = (const float*)d_in[2];
    const float* margin_vv = (const float*)d_in[3];
    const float* margin_uu = (const float*)d_in[4];
    const int*   train_u   = (const int*)d_in[5];
    const int*   pos_idx   = (const int*)d_in[6];
    const int*   neg_idx   = (const int*)d_in[7];
    const int*   nb_idx    = (const int*)d_in[8];
    const int*   nn_idx    = (const int*)d_in[9];
    const void*  pos_mask  = d_in[10];
    const void*  neg_mask  = d_in[11];
    const void*  nb_mask   = d_in[12];
    const void*  nn_mask   = d_in[13];

    float* ws  = (float*)d_ws;
    float* out = (float*)d_out;

    loss_kernel<<<BB / 2, 512, 0, stream>>>(u2e, v2e, margin_uv, margin_vv, margin_uu,
                                            train_u, pos_idx, neg_idx, nb_idx, nn_idx,
                                            pos_mask, neg_mask, nb_mask, nn_mask, ws);
    finalize_kernel<<<1, 64, 0, stream>>>(ws, out);
}

// Round 13
// 19.543 us; speedup vs baseline: 1.0324x; 1.0324x over previous
//
#include <hip/hip_runtime.h>
#include <cfloat>

#define BB   1024
#define PP   32
#define NNEG 64
#define DD   64
#define BSTR 72   // bf16 LDS row stride (144 B, 16B-aligned)
#define SSTR 68   // s_lds row stride in floats (272 B = 16 x 17, 16B-aligned rows)

static constexpr float W2c = 0.1f;

typedef __attribute__((ext_vector_type(8)))  short bf16x8;
typedef __attribute__((ext_vector_type(16))) float f32x16;

// Pack float4 -> 4 bf16 via v_cvt_pk_bf16_f32 (1 inst per 2 floats).
// Pair order within each 32-bit word is irrelevant for the Gram: the same
// k-permutation is applied to both MFMA operands (dot is invariant).
__device__ __forceinline__ uint2 pk_bf16x4(float4 v) {
    unsigned a, b;
    asm("v_cvt_pk_bf16_f32 %0, %1, %2" : "=v"(a) : "v"(v.x), "v"(v.y));
    asm("v_cvt_pk_bf16_f32 %0, %1, %2" : "=v"(b) : "v"(v.z), "v"(v.w));
    return make_uint2(a, b);
}

__device__ __forceinline__ float parse_mask(const void* p, int flag, int j) {
    if (flag == 1) return ((const unsigned char*)p)[j] ? 1.0f : 0.0f;
    if (flag == 2) return (((const float*)p)[j] != 0.0f) ? 1.0f : 0.0f;
    return ((const int*)p)[j] ? 1.0f : 0.0f;
}

// ---------------------------------------------------------------------------
// One block per batch element b; 512 threads (8 waves). Best-known structure
// (round 11: 19.63 us): barrier-free phase A with direct per-thread index
// loads, in-register stats, cvt_pk bf16 staging, MFMA Gram, vectorized
// closed-form hinge epilogue. No cross-block coherence traffic.
// ---------------------------------------------------------------------------
__global__ __launch_bounds__(512, 8) void loss_kernel(
    const float* __restrict__ u2e, const float* __restrict__ v2e,
    const float* __restrict__ margin_uv, const float* __restrict__ margin_vv,
    const float* __restrict__ margin_uu,
    const int* __restrict__ train_u, const int* __restrict__ pos_idx,
    const int* __restrict__ neg_idx, const int* __restrict__ nb_idx,
    const int* __restrict__ nn_idx,
    const void* __restrict__ pos_mask, const void* __restrict__ neg_mask,
    const void* __restrict__ nb_mask, const void* __restrict__ nn_mask,
    float* __restrict__ ws) {

    const int b = blockIdx.x;
    const int t = threadIdx.x;
    const int lane = t & 63;
    const int w = t >> 6;

    __shared__ __align__(16) short pn_bf[96 * BSTR];   // rows 0..31 p, 32..95 n (bf16)
    __shared__ __align__(16) float s_lds[PP * SSTR];   // Gram output S[i][k]
    __shared__ __align__(16) float d2[NNEG], n2s[NNEG], nmf[NNEG];
    __shared__ float d1[PP], p2s[PP], d1sA[PP], d2sA[PP];
    __shared__ float pmf[PP], nbmf[PP], nnmf[PP];
    __shared__ float mvp[PP], mv_arr[PP], s_srt[PP], S_suf[PP + 1];
    __shared__ float sc[2];
    __shared__ float red[8][3];

    // ---- Phase A (no barriers) -------------------------------------------
    // Wave-local mask-layout sniff over a 1KB window (waves 0-2 only).
    int flag = 0;
    if (w < 3) {
        unsigned f32h = 0, byth = 0;
        #pragma unroll
        for (int i2 = 0; i2 < 4; ++i2) {
            unsigned mw = ((const unsigned int*)pos_mask)[lane + 64 * i2];
            f32h |= (mw == 0x3f800000u) ? 1u : 0u;
            byth |= ((mw != 0x3f800000u) && (mw & 0xFFFFFF00u)) ? 1u : 0u;
        }
        flag = __any(f32h) ? 2 : (__any(byth) ? 1 : 0);
    }

    // Per-thread direct index loads (16-lane broadcast, coalesced)
    const int tu  = train_u[b];
    const int q   = t & 15;          // column chunk
    const int R0  = t >> 4;          // 0..31
    const int gi0 = pos_idx[b * PP + R0];
    const int gi1 = neg_idx[b * NNEG + R0];
    const int gi2 = neg_idx[b * NNEG + R0 + 32];
    const int row = t >> 3, sub = t & 7;
    const int sidx = (row < PP) ? nb_idx[b * PP + row] : nn_idx[b * PP + row - PP];

    // All row loads issue back-to-back (max MLP)
    const float* uR = u2e + (size_t)tu * DD;
    const float4 u4 = *(const float4*)(uR + 4 * q);
    float4 ch0 = *(const float4*)(v2e + (size_t)gi0 * DD + 4 * q);
    float4 ch1 = *(const float4*)(v2e + (size_t)gi1 * DD + 4 * q);
    float4 ch2 = *(const float4*)(v2e + (size_t)gi2 * DD + 4 * q);
    const float* rp = u2e + (size_t)sidx * DD + 8 * sub;
    const float4 e0 = *(const float4*)(rp);
    const float4 e1 = *(const float4*)(rp + 4);
    const float4 v0 = *(const float4*)(uR + 8 * sub);
    const float4 v1 = *(const float4*)(uR + 8 * sub + 4);

    // p/n row stats from gather registers + 16-lane shuffles
    {
        float sdp[3], sqp[3];
        float dx, dy, dz, dw;
        dx = ch0.x-u4.x; dy = ch0.y-u4.y; dz = ch0.z-u4.z; dw = ch0.w-u4.w;
        sdp[0] = dx*dx+dy*dy+dz*dz+dw*dw;
        sqp[0] = ch0.x*ch0.x+ch0.y*ch0.y+ch0.z*ch0.z+ch0.w*ch0.w;
        dx = ch1.x-u4.x; dy = ch1.y-u4.y; dz = ch1.z-u4.z; dw = ch1.w-u4.w;
        sdp[1] = dx*dx+dy*dy+dz*dz+dw*dw;
        sqp[1] = ch1.x*ch1.x+ch1.y*ch1.y+ch1.z*ch1.z+ch1.w*ch1.w;
        dx = ch2.x-u4.x; dy = ch2.y-u4.y; dz = ch2.z-u4.z; dw = ch2.w-u4.w;
        sdp[2] = dx*dx+dy*dy+dz*dz+dw*dw;
        sqp[2] = ch2.x*ch2.x+ch2.y*ch2.y+ch2.z*ch2.z+ch2.w*ch2.w;
        #pragma unroll
        for (int m = 1; m < 16; m <<= 1) {
            #pragma unroll
            for (int r = 0; r < 3; ++r) {
                sdp[r] += __shfl_xor(sdp[r], m);
                sqp[r] += __shfl_xor(sqp[r], m);
            }
        }
        if (q == 0) {
            d1[R0]      = sdp[0]; p2s[R0]      = sqp[0];
            d2[R0]      = sdp[1]; n2s[R0]      = sqp[1];
            d2[R0 + 32] = sdp[2]; n2s[R0 + 32] = sqp[2];
        }
    }
    // nb/nn stats: 8 lanes/row, 3-step shuffle
    {
        float dx = e0.x-v0.x, dy = e0.y-v0.y, dz = e0.z-v0.z, dw = e0.w-v0.w;
        float s = dx*dx+dy*dy+dz*dz+dw*dw;
        dx = e1.x-v1.x; dy = e1.y-v1.y; dz = e1.z-v1.z; dw = e1.w-v1.w;
        s += dx*dx+dy*dy+dz*dz+dw*dw;
        s += __shfl_xor(s, 1);
        s += __shfl_xor(s, 2);
        s += __shfl_xor(s, 4);
        if (sub == 0) { if (row < PP) d1sA[row] = s; else d2sA[row - PP] = s; }
    }
    // masks + margins (t<160: waves 0-2 only; they have `flag`)
    if (t < PP) {
        float pm = parse_mask(pos_mask, flag, b * PP + t);
        float mv = margin_vv[pos_idx[b * PP + t]];
        pmf[t] = pm; mv_arr[t] = mv;
        mvp[t] = (pm != 0.0f) ? mv : -FLT_MAX;
    } else if (t < 96) {
        nmf[t - PP] = parse_mask(neg_mask, flag, b * NNEG + (t - PP));
    } else if (t < 128) {
        nbmf[t - 96] = parse_mask(nb_mask, flag, b * PP + (t - 96));
    } else if (t < 160) {
        nnmf[t - 128] = parse_mask(nn_mask, flag, b * PP + (t - 128));
    }
    if (t == 0) { sc[0] = margin_uv[tu]; sc[1] = margin_uu[tu]; }
    // bf16 staging for MFMA via cvt_pk (1 inst per 2 floats)
    {
        *(uint2*)(pn_bf + R0 * BSTR + 4 * q)        = pk_bf16x4(ch0);
        *(uint2*)(pn_bf + (R0 + 32) * BSTR + 4 * q) = pk_bf16x4(ch1);
        *(uint2*)(pn_bf + (R0 + 64) * BSTR + 4 * q) = pk_bf16x4(ch2);
    }
    __syncthreads();   // barrier 1

    // ---- Phase B: MFMA Gram (waves 0,1) | sort + suffix scan (wave 2) ----
    if (w < 2) {
        f32x16 acc;
        #pragma unroll
        for (int i = 0; i < 16; ++i) acc[i] = 0.0f;
        const int lr = lane & 31;
        const int hi = lane >> 5;
        const short* ap = pn_bf + lr * BSTR;                    // A: m = lane&31
        const short* bp = pn_bf + (PP + 32 * w + lr) * BSTR;    // B: n = lane&31
        #pragma unroll
        for (int c = 0; c < 4; ++c) {
            const int d0 = 16 * c + 8 * hi;                     // k = 8*(lane>>5)+e
            bf16x8 a   = *(const bf16x8*)(ap + d0);
            bf16x8 bfr = *(const bf16x8*)(bp + d0);
            acc = __builtin_amdgcn_mfma_f32_32x32x16_bf16(a, bfr, acc, 0, 0, 0);
        }
        #pragma unroll
        for (int r = 0; r < 16; ++r) {
            const int m = (r & 3) + 8 * (r >> 2) + 4 * hi;      // verified C/D mapping
            s_lds[m * SSTR + 32 * w + lr] = acc[r];
        }
    } else if (w == 2 && lane < PP) {
        float vj = mvp[lane];
        int r = 0;
        #pragma unroll
        for (int j = 0; j < PP; ++j) {
            float o = mvp[j];
            r += (o < vj || (o == vj && j < lane)) ? 1 : 0;
        }
        s_srt[r] = vj;
        __threadfence_block();
        float y = s_srt[lane];
        #pragma unroll
        for (int d = 1; d < PP; d <<= 1) {
            float z = __shfl_down(y, d);
            if (lane + d < PP) y += z;
        }
        S_suf[lane] = y;
        if (lane == 0) S_suf[PP] = 0.0f;
    }
    __syncthreads();   // barrier 2

    // ---- Phase C: hinge epilogue; thread owns (i, 4*kb2..4*kb2+3) --------
    const float m_u = sc[0], m_s = sc[1];
    const float s31 = s_srt[PP - 1];
    const int kb2 = t & 15;
    const int i   = R0;
    const float d1i = d1[i], p2i = p2s[i], pmi = pmf[i];
    // Vectorized LDS reads: 4 consecutive k (16B-aligned, 2-way banks = free)
    const float4 Sv  = *(const float4*)(s_lds + i * SSTR + 4 * kb2);
    const float4 d2v = *(const float4*)(d2 + 4 * kb2);
    const float4 n2v = *(const float4*)(n2s + 4 * kb2);
    const float4 nmv = *(const float4*)(nmf + 4 * kb2);
    const float Sa[4]  = {Sv.x, Sv.y, Sv.z, Sv.w};
    const float d2a[4] = {d2v.x, d2v.y, d2v.z, d2v.w};
    const float n2a[4] = {n2v.x, n2v.y, n2v.z, n2v.w};
    const float nma[4] = {nmv.x, nmv.y, nmv.z, nmv.w};
    float loss = 0.0f;
    #pragma unroll
    for (int c = 0; c < 4; ++c) {
        const float cc = d1i - (p2i + n2a[c] - 2.0f * Sa[c]);
        const float v = -cc;
        int t0 = 0;
        #pragma unroll
        for (int st = 16; st > 0; st >>= 1)
            t0 += (s_srt[t0 + st - 1] <= v) ? st : 0;
        t0 += (s31 <= v) ? 1 : 0;
        const float inner = S_suf[t0] + (float)(PP - t0) * cc;
        const float uvh = fmaxf(m_u + d1i - d2a[c], 0.0f);
        loss += pmi * nma[c] * (inner + uvh);
    }

    // uu: 1024 pairs, 2 per thread
    #pragma unroll
    for (int rr = 0; rr < 2; ++rr) {
        int pid = t + 512 * rr;
        int ii = pid >> 5, k = pid & 31;
        loss += nbmf[ii] * nnmf[k] * fmaxf(m_s + d1sA[ii] - d2sA[k], 0.0f);
    }

    // ---- Block reduction ---------------------------------------------------
    float a2 = (t < PP) ? mv_arr[t] * pmf[t] : 0.0f;
    float a3 = (t < PP) ? pmf[t] : 0.0f;
    #pragma unroll
    for (int m = 1; m < 64; m <<= 1) {
        loss += __shfl_xor(loss, m);
        a2   += __shfl_xor(a2, m);
        a3   += __shfl_xor(a3, m);
    }
    if (lane == 0) { red[w][0] = loss; red[w][1] = a2; red[w][2] = a3; }
    __syncthreads();
    if (t == 0) {
        float S0 = 0, S2 = 0, S3 = 0;
        #pragma unroll
        for (int i2 = 0; i2 < 8; ++i2) { S0 += red[i2][0]; S2 += red[i2][1]; S3 += red[i2][2]; }
        ws[0 * BB + b] = S0;
        ws[1 * BB + b] = sc[0];
        ws[2 * BB + b] = S2;
        ws[3 * BB + b] = S3;
        ws[4 * BB + b] = sc[1];
    }
}

// ---------------------------------------------------------------------------
// Finalize: single wave, fully-coalesced float4 loads (20 KB total).
// Fixed reduction order -> deterministic output.
// ---------------------------------------------------------------------------
__global__ __launch_bounds__(64) void finalize_kernel(const float* __restrict__ ws,
                                                      float* __restrict__ out) {
    const int lane = threadIdx.x;
    float s[5];
    #pragma unroll
    for (int a = 0; a < 5; ++a) {
        const float4* w4 = (const float4*)(ws + a * BB);
        float acc = 0.0f;
        #pragma unroll
        for (int j = 0; j < 4; ++j) {
            float4 v = w4[lane + 64 * j];
            acc += v.x + v.y + v.z + v.w;
        }
        s[a] = acc;
    }
    #pragma unroll
    for (int m = 1; m < 64; m <<= 1)
        #pragma unroll
        for (int a = 0; a < 5; ++a) s[a] += __shfl_xor(s[a], m);
    if (lane == 0) {
        float loss_am = s[1] / (float)BB + s[2] / s[3] + s[4] / (float)BB;
        out[0] = s[0] + W2c * loss_am;
    }
}

extern "C" void kernel_launch(void* const* d_in, const int* in_sizes, int n_in,
                              void* d_out, int out_size, void* d_ws, size_t ws_size,
                              hipStream_t stream) {
    const float* u2e       = (const float*)d_in[0];
    const float* v2e       = (const float*)d_in[1];
    const float* margin_uv = (const float*)d_in[2];
    const float* margin_vv = (const float*)d_in[3];
    const float* margin_uu = (const float*)d_in[4];
    const int*   train_u   = (const int*)d_in[5];
    const int*   pos_idx   = (const int*)d_in[6];
    const int*   neg_idx   = (const int*)d_in[7];
    const int*   nb_idx    = (const int*)d_in[8];
    const int*   nn_idx    = (const int*)d_in[9];
    const void*  pos_mask  = d_in[10];
    const void*  neg_mask  = d_in[11];
    const void*  nb_mask   = d_in[12];
    const void*  nn_mask   = d_in[13];

    float* ws  = (float*)d_ws;
    float* out = (float*)d_out;

    loss_kernel<<<BB, 512, 0, stream>>>(u2e, v2e, margin_uv, margin_vv, margin_uu,
                                        train_u, pos_idx, neg_idx, nb_idx, nn_idx,
                                        pos_mask, neg_mask, nb_mask, nn_mask, ws);
    finalize_kernel<<<1, 64, 0, stream>>>(ws, out);
}